// Round 3
// baseline (240.038 us; speedup 1.0000x reference)
//
#include <hip/hip_runtime.h>
#include <stdint.h>

#define TT 512
#define BB 64
#define DD 1024
#define KK 32

__device__ __forceinline__ float rfl(float v) {
  return __int_as_float(__builtin_amdgcn_readfirstlane(__float_as_int(v)));
}

// Direct global->LDS copy, 16 B per lane.  LDS dest is wave-uniform base;
// HW writes base + lane*16 (linear lane order).  Zero VGPR staging cost.
__device__ __forceinline__ void gload_lds16(const float4* g, float4* l) {
  __builtin_amdgcn_global_load_lds(
      (const __attribute__((address_space(1))) uint32_t*)g,
      (__attribute__((address_space(3))) uint32_t*)l, 16, 0, 0);
}

// ---------------------------------------------------------------------------
// Kernel 1: emission.  F[m,k] = exp( x[m,:] @ W[:,k] + b[k] ).
// r8: r7 post-mortem showed LDS-issue-port bound: 1 ds_read_b128 per 4 FMAs
// -> LDS pipe demand ~5x VALU demand -> VALUBusy pinned at ~19% regardless
// of occupancy.  Fix: 2 rows per lane (acc[2][8]) so each wlo/whi W read
// feeds 16 FMAs (LDS insts per FLOP halved).  Block = 512 thr = 8 waves,
// 32 rows; wave w owns d-slice [128w,128w+128) in 4 staged 32-d chunks
// (global_load_lds, zero VGPR staging).  Grid 1024 -> 4 blocks/CU,
// 32 waves/CU (100%).  LDS 32 KB/block (4 x 32 = 128 KB/CU).  Live VGPRs
// ~50 (acc 16 + x dbuf 16 + addr) under the 64 cap of (512,8) — r6's
// spill was the ~75-reg acc[4][8]+pw structure, not the cap itself.
// 8-way cross-slice reduce reuses the W LDS after syncthreads.
// ---------------------------------------------------------------------------
__global__ __launch_bounds__(512, 8) void emit_kernel(
    const float* __restrict__ x, const float* __restrict__ W,
    const float* __restrict__ bias, float* __restrict__ F) {
  __shared__ float4 Ls4[2048];           // 32 KB: 8 waves x 256 f4 W chunk
  const int t = threadIdx.x;
  const int l = t & 63;
  const int w = t >> 6;                  // wave id = d-eighth (128 d)
  const int rg = l >> 2;                 // 16 row-groups x 2 rows
  const int kg = l & 3;                  // 4 k-groups x 8 k
  const int m0 = blockIdx.x * 32;
  const int r0 = m0 + rg * 2;

  const float* xp0 = x + (size_t)r0 * DD + w * 128;
  const float* xp1 = xp0 + DD;

  float acc[2][8];
#pragma unroll
  for (int j = 0; j < 2; ++j)
#pragma unroll
    for (int k = 0; k < 8; ++k) acc[j][k] = 0.f;

  float4 xa0 = *(const float4*)(xp0);
  float4 xa1 = *(const float4*)(xp1);

  const float4* Wg4 = (const float4*)(W) + (size_t)w * 1024;  // wave's d-slice
  float4* Lw = &Ls4[w * 256];            // wave's LDS region (wave-uniform)

#pragma unroll 1
  for (int c = 0; c < 4; ++c) {
    // ---- stage this wave's 32-d W chunk (4 KB) straight into LDS ----------
#pragma unroll
    for (int i = 0; i < 4; ++i)
      gload_lds16(Wg4 + c * 256 + i * 64 + l, Lw + i * 64);
    asm volatile("s_waitcnt vmcnt(0)" ::: "memory");

#pragma unroll
    for (int gg = 0; gg < 8; ++gg) {
      const int dl = c * 32 + gg * 4;          // d offset within wave's slice
      int nd = dl + 4; if (nd > 124) nd = 124; // clamp: last group reloads
      float4 xb0 = *(const float4*)(xp0 + nd);
      float4 xb1 = *(const float4*)(xp1 + nd);
#pragma unroll
      for (int d2 = 0; d2 < 4; ++d2) {
        const int wb = w * 256 + (gg * 4 + d2) * 8 + kg * 2;
        float4 wlo = Ls4[wb];        // 4 distinct addrs, broadcast to 16 lanes
        float4 whi = Ls4[wb + 1];
        const float x0 = ((const float*)&xa0)[d2];
        const float x1 = ((const float*)&xa1)[d2];
        acc[0][0]=fmaf(x0,wlo.x,acc[0][0]); acc[0][1]=fmaf(x0,wlo.y,acc[0][1]);
        acc[0][2]=fmaf(x0,wlo.z,acc[0][2]); acc[0][3]=fmaf(x0,wlo.w,acc[0][3]);
        acc[0][4]=fmaf(x0,whi.x,acc[0][4]); acc[0][5]=fmaf(x0,whi.y,acc[0][5]);
        acc[0][6]=fmaf(x0,whi.z,acc[0][6]); acc[0][7]=fmaf(x0,whi.w,acc[0][7]);
        acc[1][0]=fmaf(x1,wlo.x,acc[1][0]); acc[1][1]=fmaf(x1,wlo.y,acc[1][1]);
        acc[1][2]=fmaf(x1,wlo.z,acc[1][2]); acc[1][3]=fmaf(x1,wlo.w,acc[1][3]);
        acc[1][4]=fmaf(x1,whi.x,acc[1][4]); acc[1][5]=fmaf(x1,whi.y,acc[1][5]);
        acc[1][6]=fmaf(x1,whi.z,acc[1][6]); acc[1][7]=fmaf(x1,whi.w,acc[1][7]);
      }
      xa0 = xb0; xa1 = xb1;
    }
  }

  // ---- 8-way cross-slice reduce through LDS (reuses W regions) ----
  __syncthreads();
#pragma unroll
  for (int j = 0; j < 2; ++j) {
    Ls4[w * 256 + (rg * 2 + j) * 8 + kg * 2] =
        make_float4(acc[j][0], acc[j][1], acc[j][2], acc[j][3]);
    Ls4[w * 256 + (rg * 2 + j) * 8 + kg * 2 + 1] =
        make_float4(acc[j][4], acc[j][5], acc[j][6], acc[j][7]);
  }
  __syncthreads();
  if (t < 256) {
    const int rr = t >> 3;         // 32 rows
    const int kc = t & 7;          // 8 float4 per row
    float4 s = Ls4[rr * 8 + kc];
#pragma unroll
    for (int q = 1; q < 8; ++q) {
      float4 a = Ls4[q * 256 + rr * 8 + kc];
      s.x += a.x; s.y += a.y; s.z += a.z; s.w += a.w;
    }
    float4 bv = *(const float4*)(bias + kc * 4);
    float4 e;
    e.x = __expf(s.x + bv.x); e.y = __expf(s.y + bv.y);
    e.z = __expf(s.z + bv.z); e.w = __expf(s.w + bv.w);
    ((float4*)(F + (size_t)(m0 + rr) * KK))[kc] = e;
  }
}

// ---------------------------------------------------------------------------
// Kernel 2: segmented scaled linear-domain forward/backward recursions.
// (unchanged — correct, off the critical path)
// ---------------------------------------------------------------------------
__global__ __launch_bounds__(64) void scan_kernel(
    const float* __restrict__ F, const float* __restrict__ U,
    float* __restrict__ A, float* __restrict__ Bw) {
  __shared__ __align__(16) float cur[KK];
  const int l = threadIdx.x;
  const int kk = l & 31;
  const int h = l >> 5;
  const int seg = blockIdx.x & 15;
  const int b = (blockIdx.x >> 4) & 63;
  const int dir = blockIdx.x >> 10;

  const float* Fb = F + (size_t)b * TT * KK;
  float V[16];

  if (dir == 0) {
    float* Ab = A + (size_t)b * TT * KK;
#pragma unroll
    for (int j = 0; j < 16; ++j) V[j] = __expf(U[(h * 16 + j) * KK + kk]);
    const int lo = seg * 32, hi = seg * 32 + 31;
    const int t0 = (seg == 0) ? 0 : lo - 17;
    float a = Fb[t0 * KK + kk];
    cur[kk] = a;
    if (seg == 0 && l < 32) Ab[l] = a;
    __builtin_amdgcn_wave_barrier();

#define FSTEP(fv, tcur)                                                     \
    {                                                                       \
      const float4* c4 = (const float4*)cur;                                \
      float4 y0 = c4[h*4+0], y1 = c4[h*4+1], y2 = c4[h*4+2], y3 = c4[h*4+3];\
      float r = __builtin_amdgcn_rcpf(rfl(y0.x));                           \
      float s0 = fmaf(y0.x, V[0],  fmaf(y0.y, V[1],                         \
                 fmaf(y0.z, V[2],  y0.w * V[3])));                          \
      float s1 = fmaf(y1.x, V[4],  fmaf(y1.y, V[5],                         \
                 fmaf(y1.z, V[6],  y1.w * V[7])));                          \
      float s2 = fmaf(y2.x, V[8],  fmaf(y2.y, V[9],                         \
                 fmaf(y2.z, V[10], y2.w * V[11])));                         \
      float s3 = fmaf(y3.x, V[12], fmaf(y3.y, V[13],                        \
                 fmaf(y3.z, V[14], y3.w * V[15])));                         \
      float s = (s0 + s1) + (s2 + s3);                                      \
      s += __shfl_xor(s, 32);                                               \
      a = s * ((fv) * r);                                                   \
      cur[kk] = a;                                                          \
      __builtin_amdgcn_wave_barrier();                                      \
      if ((tcur) >= lo && l < 32) Ab[(tcur) * KK + l] = a;                  \
    }

    int t = t0 + 1;
    float f0 = Fb[t * KK + kk],       f1 = Fb[(t + 1) * KK + kk];
    float f2 = Fb[(t + 2) * KK + kk], f3 = Fb[(t + 3) * KK + kk];
    for (; t + 3 <= hi; t += 4) {
      int tn = t + 4;
      int u0 = tn     > hi ? hi : tn;
      int u1 = tn + 1 > hi ? hi : tn + 1;
      int u2 = tn + 2 > hi ? hi : tn + 2;
      int u3 = tn + 3 > hi ? hi : tn + 3;
      float n0 = Fb[u0 * KK + kk], n1 = Fb[u1 * KK + kk];
      float n2 = Fb[u2 * KK + kk], n3 = Fb[u3 * KK + kk];
      FSTEP(f0, t); FSTEP(f1, t + 1); FSTEP(f2, t + 2); FSTEP(f3, t + 3);
      f0 = n0; f1 = n1; f2 = n2; f3 = n3;
    }
    if (t <= hi) { FSTEP(f0, t); ++t; }
    if (t <= hi) { FSTEP(f1, t); ++t; }
    if (t <= hi) { FSTEP(f2, t); ++t; }
#undef FSTEP
  } else {
    const int b2 = b;
    float* Bb = Bw + (size_t)b2 * TT * KK;
#pragma unroll
    for (int j = 0; j < 16; ++j) V[j] = __expf(U[kk * KK + h * 16 + j]);
    const int lo = seg * 32;
    const int hs = seg * 32 + 31;
    const int t1 = (seg == 15) ? (TT - 1) : (lo + 48);
    float g = Fb[t1 * KK + kk];
    cur[kk] = g;
    if (seg == 15 && l < 32) Bb[(TT - 1) * KK + l] = 1.0f;
    __builtin_amdgcn_wave_barrier();

#define BSTEP(fv, tcur)                                                     \
    {                                                                       \
      const float4* c4 = (const float4*)cur;                                \
      float4 y0 = c4[h*4+0], y1 = c4[h*4+1], y2 = c4[h*4+2], y3 = c4[h*4+3];\
      float r = __builtin_amdgcn_rcpf(rfl(y0.x));                           \
      float s0 = fmaf(y0.x, V[0],  fmaf(y0.y, V[1],                         \
                 fmaf(y0.z, V[2],  y0.w * V[3])));                          \
      float s1 = fmaf(y1.x, V[4],  fmaf(y1.y, V[5],                         \
                 fmaf(y1.z, V[6],  y1.w * V[7])));                          \
      float s2 = fmaf(y2.x, V[8],  fmaf(y2.y, V[9],                         \
                 fmaf(y2.z, V[10], y2.w * V[11])));                         \
      float s3 = fmaf(y3.x, V[12], fmaf(y3.y, V[13],                        \
                 fmaf(y3.z, V[14], y3.w * V[15])));                         \
      float s = (s0 + s1) + (s2 + s3);                                      \
      s += __shfl_xor(s, 32);                                               \
      float bnew = s * r;                                                   \
      g = bnew * (fv);                                                      \
      cur[kk] = g;                                                          \
      __builtin_amdgcn_wave_barrier();                                      \
      if ((tcur) <= hs && l < 32) Bb[(tcur) * KK + l] = bnew;               \
    }

    int t = t1 - 1;
    float f0 = Fb[t * KK + kk],       f1 = Fb[(t - 1) * KK + kk];
    float f2 = Fb[(t - 2) * KK + kk], f3 = Fb[(t - 3) * KK + kk];
    for (; t - 3 >= lo; t -= 4) {
      int tn = t - 4;
      int u0 = tn     < 0 ? 0 : tn;
      int u1 = tn - 1 < 0 ? 0 : tn - 1;
      int u2 = tn - 2 < 0 ? 0 : tn - 2;
      int u3 = tn - 3 < 0 ? 0 : tn - 3;
      float n0 = Fb[u0 * KK + kk], n1 = Fb[u1 * KK + kk];
      float n2 = Fb[u2 * KK + kk], n3 = Fb[u3 * KK + kk];
      BSTEP(f0, t); BSTEP(f1, t - 1); BSTEP(f2, t - 2); BSTEP(f3, t - 3);
      f0 = n0; f1 = n1; f2 = n2; f3 = n3;
    }
    if (t >= lo) { BSTEP(f0, t); --t; }
    if (t >= lo) { BSTEP(f1, t); --t; }
    if (t >= lo) { BSTEP(f2, t); --t; }
#undef BSTEP
  }
}

// ---------------------------------------------------------------------------
// Kernel 3: marginals.  out[m,k] = A[m,k]*B[m,k] / sum_k' A[m,k']*B[m,k'].
// ---------------------------------------------------------------------------
__global__ __launch_bounds__(256) void combine_kernel(
    const float* __restrict__ Bw, float* __restrict__ out) {
  size_t i = (size_t)blockIdx.x * 256 + threadIdx.x;
  float p = out[i] * Bw[i];
  float ssum = p;
  ssum += __shfl_xor(ssum, 1);
  ssum += __shfl_xor(ssum, 2);
  ssum += __shfl_xor(ssum, 4);
  ssum += __shfl_xor(ssum, 8);
  ssum += __shfl_xor(ssum, 16);
  out[i] = p / ssum;
}

extern "C" void kernel_launch(void* const* d_in, const int* in_sizes, int n_in,
                              void* d_out, int out_size, void* d_ws, size_t ws_size,
                              hipStream_t stream) {
  const float* x = (const float*)d_in[0];   // [B,T,D]
  const float* W = (const float*)d_in[1];   // [D,K]
  const float* U = (const float*)d_in[2];   // [K,K]
  const float* b = (const float*)d_in[3];   // [K]
  float* out = (float*)d_out;               // [B,T,K] — doubles as A scratch
  float* F = (float*)d_ws;                  // exp(emissions), [B*T, K] (4 MB)
  float* Bw = F + (size_t)BB * TT * KK;     // backward messages    (4 MB)

  emit_kernel<<<1024, 512, 0, stream>>>(x, W, b, F);
  scan_kernel<<<2048, 64, 0, stream>>>(F, U, out, Bw);
  combine_kernel<<<(BB * TT * KK) / 256, 256, 0, stream>>>(Bw, out);
}

// Round 4
// 219.602 us; speedup vs baseline: 1.0931x; 1.0931x over previous
//
#include <hip/hip_runtime.h>
#include <stdint.h>

#define TT 512
#define BB 64
#define DD 1024
#define KK 32

__device__ __forceinline__ float rfl(float v) {
  return __int_as_float(__builtin_amdgcn_readfirstlane(__float_as_int(v)));
}

// Direct global->LDS copy, 16 B per lane.  LDS dest is wave-uniform base;
// HW writes base + lane*16 (linear lane order).  Zero VGPR staging cost.
__device__ __forceinline__ void gload_lds16(const float4* g, float4* l) {
  __builtin_amdgcn_global_load_lds(
      (const __attribute__((address_space(1))) uint32_t*)g,
      (__attribute__((address_space(3))) uint32_t*)l, 16, 0, 0);
}

// ---------------------------------------------------------------------------
// Kernel 1: emission.  F[m,k] = exp( x[m,:] @ W[:,k] + b[k] ).
// r9: rounds 5-8 all hit ~83us regardless of occupancy (19->70%) or LDS:FMA
// ratio -> the invariant was the x path: scattered 16-line depth-1 register
// prefetch loads (exposed ~900cy HBM latency per gg) + per-chunk vmcnt(0)
// drains.  Fix: x AND W staged via global_load_lds, chunk-level double
// buffer, counted vmcnt(6) in steady state (never 0 in the loop) -> one
// full chunk of compute (~1-2K cy) covers HBM latency; x staging is
// coalesced 64B-per-row segments, zero redundancy.
//   Block 256 thr = 4 waves; wave w owns d-quarter [256w,256w+256);
//   64 rows/block; lane: rg=l>>2 (16 groups x 4 rows), kg=l&3 (8 k each).
//   Chunk = 16 d: W 2KB (2 gload_lds), x 4KB (4 gload_lds).
//   x LDS rows are 64B (16-word stride = all-same-bank), so x is
//   XOR-swizzled by ((row>>2)&3)<<4 bytes via pre-swizzled GLOBAL source
//   (gload_lds dest must stay linear); read applies same XOR; residual
//   4-way conflict on x reads only.  Per gg: 12 ds_read_b128 : 128 FMA.
//   LDS 48KB/block; grid 512 (= 2 blocks/CU of work) -> occupancy ~25-37%
//   BY DESIGN; async staging needs only ~2 waves/SIMD.
//   d-accumulation order identical to r7 (asc per quarter, quarters q0..q3)
//   -> F bitwise unchanged -> absmax unchanged.
// ---------------------------------------------------------------------------
__global__ __launch_bounds__(256, 4) void emit_kernel(
    const float* __restrict__ x, const float* __restrict__ W,
    const float* __restrict__ bias, float* __restrict__ F) {
  __shared__ float4 Ls4[3072];   // 48KB: per-wave 768 f4 = W[2][128] + X[2][256]
  const int t = threadIdx.x;
  const int l = t & 63;
  const int w = t >> 6;                  // wave id = d-quarter
  const int rg = l >> 2;                 // 16 row-groups x 4 rows
  const int kg = l & 3;                  // 4 k-groups x 8 k
  const int m0 = blockIdx.x * 64;

  const int wb4 = w * 768;
  float4* Lw = &Ls4[wb4];                // W chunks: [2][128] f4
  float4* Lx = &Ls4[wb4 + 256];          // x chunks: [2][256] f4

  // Per-lane staging sources.
  // W inst j2: d = w*256 + c*16 + 8*j2 + (l>>3), k4 = l&7  (contiguous 128B/d)
  const float* Wlane = W + (size_t)(w * 256 + (l >> 3)) * KK + (l & 7) * 4;
  // x inst i: row = m0 + 16*i + (l>>2); stored pos l&3 must hold d-group
  // (l&3)^key, key=(row>>2)&3=(l>>4)&3  -> pre-swizzle the global d-offset.
  const float* Xlane = x + (size_t)(m0 + (l >> 2)) * DD + w * 256
                         + 4 * ((l & 3) ^ ((l >> 4) & 3));

#define STAGE(c, p) do {                                                    \
    const float* ws_ = Wlane + (size_t)(c) * 16 * KK;                       \
    gload_lds16((const float4*)(ws_),           Lw + (p) * 128);            \
    gload_lds16((const float4*)(ws_ + 8 * KK),  Lw + (p) * 128 + 64);       \
    const float* xs_ = Xlane + (c) * 16;                                    \
    gload_lds16((const float4*)(xs_),               Lx + (p) * 256);        \
    gload_lds16((const float4*)(xs_ + 16 * DD),     Lx + (p) * 256 + 64);   \
    gload_lds16((const float4*)(xs_ + 32 * DD),     Lx + (p) * 256 + 128);  \
    gload_lds16((const float4*)(xs_ + 48 * DD),     Lx + (p) * 256 + 192);  \
  } while (0)

#define COMPUTE(p) do {                                                     \
    const float4* Wb = Lw + (p) * 128;                                      \
    const float4* Xb = Lx + (p) * 256;                                      \
    _Pragma("unroll")                                                       \
    for (int gg = 0; gg < 4; ++gg) {                                        \
      const int xsw = gg ^ (rg & 3);     /* XOR-swizzled 16B slot */        \
      float4 xr[4];                                                         \
      _Pragma("unroll")                                                     \
      for (int j = 0; j < 4; ++j) xr[j] = Xb[(4 * rg + j) * 4 + xsw];       \
      _Pragma("unroll")                                                     \
      for (int dd = 0; dd < 4; ++dd) {                                      \
        float4 wlo = Wb[(gg * 4 + dd) * 8 + kg * 2];                        \
        float4 whi = Wb[(gg * 4 + dd) * 8 + kg * 2 + 1];                    \
        _Pragma("unroll")                                                   \
        for (int j = 0; j < 4; ++j) {                                       \
          const float xv = ((const float*)&xr[j])[dd];                      \
          acc[j][0] = fmaf(xv, wlo.x, acc[j][0]);                           \
          acc[j][1] = fmaf(xv, wlo.y, acc[j][1]);                           \
          acc[j][2] = fmaf(xv, wlo.z, acc[j][2]);                           \
          acc[j][3] = fmaf(xv, wlo.w, acc[j][3]);                           \
          acc[j][4] = fmaf(xv, whi.x, acc[j][4]);                           \
          acc[j][5] = fmaf(xv, whi.y, acc[j][5]);                           \
          acc[j][6] = fmaf(xv, whi.z, acc[j][6]);                           \
          acc[j][7] = fmaf(xv, whi.w, acc[j][7]);                           \
        }                                                                   \
      }                                                                     \
    }                                                                       \
  } while (0)

  float acc[4][8];
#pragma unroll
  for (int j = 0; j < 4; ++j)
#pragma unroll
    for (int k = 0; k < 8; ++k) acc[j][k] = 0.f;

  STAGE(0, 0);
  STAGE(1, 1);

#pragma unroll 1
  for (int c = 0; c < 14; ++c) {
    const int p = c & 1;
    // chunk c's 6 loads are the oldest outstanding; keep c+1's 6 in flight.
    asm volatile("s_waitcnt vmcnt(6)" ::: "memory");
    COMPUTE(p);
    asm volatile("" ::: "memory");     // keep STAGE after the ds_reads
    STAGE(c + 2, p);                   // refill the buffer just consumed
  }
  asm volatile("s_waitcnt vmcnt(6)" ::: "memory");
  COMPUTE(0);                          // chunk 14
  asm volatile("s_waitcnt vmcnt(0)" ::: "memory");
  COMPUTE(1);                          // chunk 15

#undef STAGE
#undef COMPUTE

  // ---- 4-way cross-quarter reduce through LDS (reuses staging regions) ----
  __syncthreads();
#pragma unroll
  for (int j = 0; j < 4; ++j) {
    Ls4[wb4 + (4 * rg + j) * 8 + kg * 2] =
        make_float4(acc[j][0], acc[j][1], acc[j][2], acc[j][3]);
    Ls4[wb4 + (4 * rg + j) * 8 + kg * 2 + 1] =
        make_float4(acc[j][4], acc[j][5], acc[j][6], acc[j][7]);
  }
  __syncthreads();
#pragma unroll
  for (int rep = 0; rep < 2; ++rep) {
    const int idx = t + rep * 256;     // f4 index 0..511
    const int rr = idx >> 3;           // 64 rows
    const int kc = idx & 7;            // 8 f4 per row
    float4 s = Ls4[idx];
#pragma unroll
    for (int q = 1; q < 4; ++q) {
      float4 a = Ls4[q * 768 + idx];
      s.x += a.x; s.y += a.y; s.z += a.z; s.w += a.w;
    }
    float4 bv = *(const float4*)(bias + kc * 4);
    float4 e;
    e.x = __expf(s.x + bv.x); e.y = __expf(s.y + bv.y);
    e.z = __expf(s.z + bv.z); e.w = __expf(s.w + bv.w);
    ((float4*)(F + (size_t)(m0 + rr) * KK))[kc] = e;
  }
}

// ---------------------------------------------------------------------------
// Kernel 2: segmented scaled linear-domain forward/backward recursions.
// (unchanged — correct, off the critical path)
// ---------------------------------------------------------------------------
__global__ __launch_bounds__(64) void scan_kernel(
    const float* __restrict__ F, const float* __restrict__ U,
    float* __restrict__ A, float* __restrict__ Bw) {
  __shared__ __align__(16) float cur[KK];
  const int l = threadIdx.x;
  const int kk = l & 31;
  const int h = l >> 5;
  const int seg = blockIdx.x & 15;
  const int b = (blockIdx.x >> 4) & 63;
  const int dir = blockIdx.x >> 10;

  const float* Fb = F + (size_t)b * TT * KK;
  float V[16];

  if (dir == 0) {
    float* Ab = A + (size_t)b * TT * KK;
#pragma unroll
    for (int j = 0; j < 16; ++j) V[j] = __expf(U[(h * 16 + j) * KK + kk]);
    const int lo = seg * 32, hi = seg * 32 + 31;
    const int t0 = (seg == 0) ? 0 : lo - 17;
    float a = Fb[t0 * KK + kk];
    cur[kk] = a;
    if (seg == 0 && l < 32) Ab[l] = a;
    __builtin_amdgcn_wave_barrier();

#define FSTEP(fv, tcur)                                                     \
    {                                                                       \
      const float4* c4 = (const float4*)cur;                                \
      float4 y0 = c4[h*4+0], y1 = c4[h*4+1], y2 = c4[h*4+2], y3 = c4[h*4+3];\
      float r = __builtin_amdgcn_rcpf(rfl(y0.x));                           \
      float s0 = fmaf(y0.x, V[0],  fmaf(y0.y, V[1],                         \
                 fmaf(y0.z, V[2],  y0.w * V[3])));                          \
      float s1 = fmaf(y1.x, V[4],  fmaf(y1.y, V[5],                         \
                 fmaf(y1.z, V[6],  y1.w * V[7])));                          \
      float s2 = fmaf(y2.x, V[8],  fmaf(y2.y, V[9],                         \
                 fmaf(y2.z, V[10], y2.w * V[11])));                         \
      float s3 = fmaf(y3.x, V[12], fmaf(y3.y, V[13],                        \
                 fmaf(y3.z, V[14], y3.w * V[15])));                         \
      float s = (s0 + s1) + (s2 + s3);                                      \
      s += __shfl_xor(s, 32);                                               \
      a = s * ((fv) * r);                                                   \
      cur[kk] = a;                                                          \
      __builtin_amdgcn_wave_barrier();                                      \
      if ((tcur) >= lo && l < 32) Ab[(tcur) * KK + l] = a;                  \
    }

    int t = t0 + 1;
    float f0 = Fb[t * KK + kk],       f1 = Fb[(t + 1) * KK + kk];
    float f2 = Fb[(t + 2) * KK + kk], f3 = Fb[(t + 3) * KK + kk];
    for (; t + 3 <= hi; t += 4) {
      int tn = t + 4;
      int u0 = tn     > hi ? hi : tn;
      int u1 = tn + 1 > hi ? hi : tn + 1;
      int u2 = tn + 2 > hi ? hi : tn + 2;
      int u3 = tn + 3 > hi ? hi : tn + 3;
      float n0 = Fb[u0 * KK + kk], n1 = Fb[u1 * KK + kk];
      float n2 = Fb[u2 * KK + kk], n3 = Fb[u3 * KK + kk];
      FSTEP(f0, t); FSTEP(f1, t + 1); FSTEP(f2, t + 2); FSTEP(f3, t + 3);
      f0 = n0; f1 = n1; f2 = n2; f3 = n3;
    }
    if (t <= hi) { FSTEP(f0, t); ++t; }
    if (t <= hi) { FSTEP(f1, t); ++t; }
    if (t <= hi) { FSTEP(f2, t); ++t; }
#undef FSTEP
  } else {
    const int b2 = b;
    float* Bb = Bw + (size_t)b2 * TT * KK;
#pragma unroll
    for (int j = 0; j < 16; ++j) V[j] = __expf(U[kk * KK + h * 16 + j]);
    const int lo = seg * 32;
    const int hs = seg * 32 + 31;
    const int t1 = (seg == 15) ? (TT - 1) : (lo + 48);
    float g = Fb[t1 * KK + kk];
    cur[kk] = g;
    if (seg == 15 && l < 32) Bb[(TT - 1) * KK + l] = 1.0f;
    __builtin_amdgcn_wave_barrier();

#define BSTEP(fv, tcur)                                                     \
    {                                                                       \
      const float4* c4 = (const float4*)cur;                                \
      float4 y0 = c4[h*4+0], y1 = c4[h*4+1], y2 = c4[h*4+2], y3 = c4[h*4+3];\
      float r = __builtin_amdgcn_rcpf(rfl(y0.x));                           \
      float s0 = fmaf(y0.x, V[0],  fmaf(y0.y, V[1],                         \
                 fmaf(y0.z, V[2],  y0.w * V[3])));                          \
      float s1 = fmaf(y1.x, V[4],  fmaf(y1.y, V[5],                         \
                 fmaf(y1.z, V[6],  y1.w * V[7])));                          \
      float s2 = fmaf(y2.x, V[8],  fmaf(y2.y, V[9],                         \
                 fmaf(y2.z, V[10], y2.w * V[11])));                         \
      float s3 = fmaf(y3.x, V[12], fmaf(y3.y, V[13],                        \
                 fmaf(y3.z, V[14], y3.w * V[15])));                         \
      float s = (s0 + s1) + (s2 + s3);                                      \
      s += __shfl_xor(s, 32);                                               \
      float bnew = s * r;                                                   \
      g = bnew * (fv);                                                      \
      cur[kk] = g;                                                          \
      __builtin_amdgcn_wave_barrier();                                      \
      if ((tcur) <= hs && l < 32) Bb[(tcur) * KK + l] = bnew;               \
    }

    int t = t1 - 1;
    float f0 = Fb[t * KK + kk],       f1 = Fb[(t - 1) * KK + kk];
    float f2 = Fb[(t - 2) * KK + kk], f3 = Fb[(t - 3) * KK + kk];
    for (; t - 3 >= lo; t -= 4) {
      int tn = t - 4;
      int u0 = tn     < 0 ? 0 : tn;
      int u1 = tn - 1 < 0 ? 0 : tn - 1;
      int u2 = tn - 2 < 0 ? 0 : tn - 2;
      int u3 = tn - 3 < 0 ? 0 : tn - 3;
      float n0 = Fb[u0 * KK + kk], n1 = Fb[u1 * KK + kk];
      float n2 = Fb[u2 * KK + kk], n3 = Fb[u3 * KK + kk];
      BSTEP(f0, t); BSTEP(f1, t - 1); BSTEP(f2, t - 2); BSTEP(f3, t - 3);
      f0 = n0; f1 = n1; f2 = n2; f3 = n3;
    }
    if (t >= lo) { BSTEP(f0, t); --t; }
    if (t >= lo) { BSTEP(f1, t); --t; }
    if (t >= lo) { BSTEP(f2, t); --t; }
#undef BSTEP
  }
}

// ---------------------------------------------------------------------------
// Kernel 3: marginals.  out[m,k] = A[m,k]*B[m,k] / sum_k' A[m,k']*B[m,k'].
// ---------------------------------------------------------------------------
__global__ __launch_bounds__(256) void combine_kernel(
    const float* __restrict__ Bw, float* __restrict__ out) {
  size_t i = (size_t)blockIdx.x * 256 + threadIdx.x;
  float p = out[i] * Bw[i];
  float ssum = p;
  ssum += __shfl_xor(ssum, 1);
  ssum += __shfl_xor(ssum, 2);
  ssum += __shfl_xor(ssum, 4);
  ssum += __shfl_xor(ssum, 8);
  ssum += __shfl_xor(ssum, 16);
  out[i] = p / ssum;
}

extern "C" void kernel_launch(void* const* d_in, const int* in_sizes, int n_in,
                              void* d_out, int out_size, void* d_ws, size_t ws_size,
                              hipStream_t stream) {
  const float* x = (const float*)d_in[0];   // [B,T,D]
  const float* W = (const float*)d_in[1];   // [D,K]
  const float* U = (const float*)d_in[2];   // [K,K]
  const float* b = (const float*)d_in[3];   // [K]
  float* out = (float*)d_out;               // [B,T,K] — doubles as A scratch
  float* F = (float*)d_ws;                  // exp(emissions), [B*T, K] (4 MB)
  float* Bw = F + (size_t)BB * TT * KK;     // backward messages    (4 MB)

  emit_kernel<<<512, 256, 0, stream>>>(x, W, b, F);
  scan_kernel<<<2048, 64, 0, stream>>>(F, U, out, Bw);
  combine_kernel<<<(BB * TT * KK) / 256, 256, 0, stream>>>(Bw, out);
}